// Round 6
// baseline (333.714 us; speedup 1.0000x reference)
//
#include <hip/hip_runtime.h>
#include <hip/hip_fp16.h>
#include <cfloat>

// NearestNeighborGraph: S=16, N=2048, D=64, K=16.
// Round-14: single fused kernel. Rounds 10-13 post-mortems: every in-kernel
// lever (occupancy 2x, VALU-work 3x cut, LDS scoreboard deletion, FETCH 4x
// cut) left the knn dispatch at ~160us -> attack the OTHER ~55us: the prep
// kernel + inter-kernel gap carried since round 1.
//  - prep deleted: each block computes its sample's x2[2048] into LDS with
//    the bit-identical rotated fmaf chains (8 rows/thread).
//  - hh (4MB f16 copy) deleted: i/j fragments convert f32->f16 inline with
//    scalar (_Float16) casts == prep's cvt (RTN) -> identical f16 bits ->
//    identical accs/tau/rings -> output bit-identical to rounds 11-13.
//  - XCD sample-affinity swizzle kept (FETCH 59->15.7MB proven r13);
//    per-XCD working set = 2 samples x 512KB f32 = 1MB, L2-resident.
//  - simple unroll-2 loops (r12 == r13 showed pipeline depth is moot).

typedef _Float16 half8 __attribute__((ext_vector_type(8)));
typedef float    f32x4 __attribute__((ext_vector_type(4)));

constexpr int NS = 16, NP = 2048, ND = 64, KK = 16;
constexpr int NWV = 4;              // waves per block
constexpr int NT  = NWV * 64;       // 256 threads
constexpr int RB  = 32;             // rows (i) per block
constexpr int ITN = RB / 16;        // 2 i-tiles
constexpr int JW  = NP / NWV;       // 512 j per wave
constexpr int NJT = JW / 16;        // 32 j-tiles per wave
constexpr int MS  = 17;             // merge-tree stride
constexpr int RCAP = 128;           // candidate ring slots per row
constexpr int RSTR = RCAP + 1;      // ring stride
constexpr float MARGIN = 1.0f;

// lexicographic (d2, j) insert == top_k tie-break (lowest index on equal d2)
__device__ __forceinline__ bool lexlt(float a, int ja, float b, int jb)
{
    return (a < b) || (a == b && ja < jb);
}
__device__ __forceinline__ void insert16x(float (&d)[KK], int (&ix)[KK],
                                          float v, int j)
{
    #pragma unroll
    for (int p = KK - 1; p > 0; --p) {
        bool sh = lexlt(v, j, d[p - 1], ix[p - 1]);
        bool he = lexlt(v, j, d[p], ix[p]);
        float nd = sh ? d[p - 1] : (he ? v : d[p]);
        int   ni = sh ? ix[p - 1] : (he ? j : ix[p]);
        d[p] = nd; ix[p] = ni;
    }
    if (lexlt(v, j, d[0], ix[0])) { d[0] = v; ix[0] = j; }
}

__device__ __forceinline__ half8 cvt8(float4 a, float4 b)
{
    half8 p;
    p[0] = (_Float16)a.x; p[1] = (_Float16)a.y;
    p[2] = (_Float16)a.z; p[3] = (_Float16)a.w;
    p[4] = (_Float16)b.x; p[5] = (_Float16)b.y;
    p[6] = (_Float16)b.z; p[7] = (_Float16)b.w;
    return p;
}

__global__ __launch_bounds__(NT, 4)
void knn_fused(const float* __restrict__ h, float* __restrict__ out)
{
    // 8544 floats = 34176 B -> 4 blocks/CU
    __shared__ __align__(16) float smem[8544];
    float* ldsx2  = smem;                    // [0,2048)
    float* mw     = smem + 2048;             // [2048,2176)  4 waves x 32 rows
    float* ldsthr = smem + 2176;             // [2176,2208)
    int*   rcnt   = (int*)(smem + 2208);     // [2208,2240)
    int*   ring   = (int*)(smem + 2240);     // [2240,6368)  32 x 129
    float* md     = smem + 6368;             // [6368,7456)  2 x 32 x 17
    int*   mi     = (int*)(smem + 7456);     // [7456,8544)

    const int t   = threadIdx.x;
    const int ln  = t & 63;
    const int qd  = ln >> 4;                 // j-subslice within wave
    const int cl  = ln & 15;                 // i within 16-tile (swapped D col)
    const int q   = t >> 6;                  // wave id (j-quarter)
    const int row = ln & 31;                 // lane's rescue row
    const int jh  = ln >> 5;                 // rescue worker split
    // XCD sample-affinity swizzle (bijective): sample s -> XCD (s&7),
    // assuming hardware round-robin bid->XCD bid%8 (perf heuristic only).
    const int bid = blockIdx.x;
    const int xcd = bid & 7;
    const int kb  = bid >> 3;                // 0..127
    const int s   = xcd + ((kb & 1) << 3);   // 0..15
    const int rb  = kb >> 1;                 // 0..63
    const int rowbase = rb * RB;             // block's 32 i-rows (sample-local)
    const float* __restrict__ hs = h + (size_t)s * NP * ND;

    // init ring counts
    if (t < RB) rcnt[t] = 0;

    // ---- phase 0: sample x2 into LDS (bit-identical rotated fmaf chain) ----
    #pragma unroll 1
    for (int u = 0; u < 8; ++u) {
        const int r = t * 8 + u;
        const float4* rowp = (const float4*)(hs + (size_t)r * ND);
        const int ph = r & 15;               // == (s*NP + r) & 15
        float a0 = 0.f, a1 = 0.f, a2 = 0.f, a3 = 0.f;
        #pragma unroll
        for (int k = 0; k < 16; ++k) {
            float4 v = rowp[(k + ph) & 15];
            a0 = fmaf(v.x, v.x, a0); a1 = fmaf(v.y, v.y, a1);
            a2 = fmaf(v.z, v.z, a2); a3 = fmaf(v.w, v.w, a3);
        }
        ldsx2[r] = (a0 + a1) + (a2 + a3);
    }

    // i-fragments (the MFMA *B* operand): lane holds I[n=cl][k=qd*8..+7],
    // converted inline f32->f16 (same cvt bits as the old prep kernel)
    half8 ifr[ITN][2];
    #pragma unroll
    for (int it = 0; it < ITN; ++it) {
        const float* ap = hs + (size_t)(rowbase + it * 16 + cl) * ND + qd * 8;
        ifr[it][0] = cvt8(*(const float4*)(ap),      *(const float4*)(ap + 4));
        ifr[it][1] = cvt8(*(const float4*)(ap + 32), *(const float4*)(ap + 36));
    }
    __syncthreads();   // ldsx2 ready

    const int jbase = q * JW;
    const float* __restrict__ jrow0 = hs + (size_t)(jbase + cl) * ND + qd * 8;

    // ===== stage A: swapped MFMA scan; per-lane top-4 of d2' in registers ====
    // d2' = x2j - 2*dot  (x2i dropped: per-row constant, rank-invariant).
    float t1[ITN], t2[ITN], t3[ITN], t4[ITN];
    #pragma unroll
    for (int it = 0; it < ITN; ++it)
        { t1[it] = FLT_MAX; t2[it] = FLT_MAX; t3[it] = FLT_MAX; t4[it] = FLT_MAX; }

    #pragma unroll 2
    for (int jt = 0; jt < NJT; ++jt) {
        const float* bp = jrow0 + (size_t)jt * (16 * ND);
        float4 va = *(const float4*)(bp);
        float4 vb = *(const float4*)(bp + 4);
        float4 vc = *(const float4*)(bp + 32);
        float4 vd = *(const float4*)(bp + 36);
        f32x4 xq = *(const f32x4*)(ldsx2 + jbase + jt * 16 + qd * 4);
        half8 jlo = cvt8(va, vb);
        half8 jhi = cvt8(vc, vd);

        #pragma unroll
        for (int it = 0; it < ITN; ++it) {
            f32x4 acc;
            acc = __builtin_amdgcn_mfma_f32_16x16x32_f16(
                      jlo, ifr[it][0], (f32x4){0.f, 0.f, 0.f, 0.f}, 0, 0, 0);
            acc = __builtin_amdgcn_mfma_f32_16x16x32_f16(
                      jhi, ifr[it][1], acc, 0, 0, 0);
            #pragma unroll
            for (int r = 0; r < 4; ++r) {
                float v  = fmaf(-2.f, acc[r], xq[r]);
                float n1 = fminf(t1[it], v);
                float n2 = __builtin_amdgcn_fmed3f(t1[it], t2[it], v);
                float n3 = __builtin_amdgcn_fmed3f(t2[it], t3[it], v);
                float n4 = __builtin_amdgcn_fmed3f(t3[it], t4[it], v);
                t1[it] = n1; t2[it] = n2; t3[it] = n3; t4[it] = n4;
            }
        }
    }

    // merge the 4 qd sub-lists (sorted 4s) -> wave's exact top-4 of 512
    #pragma unroll
    for (int it = 0; it < ITN; ++it) {
        #pragma unroll
        for (int lvl = 0; lvl < 2; ++lvl) {
            const int mask = 16 << lvl;
            float b1 = __shfl_xor(t1[it], mask), b2 = __shfl_xor(t2[it], mask);
            float b3 = __shfl_xor(t3[it], mask), b4 = __shfl_xor(t4[it], mask);
            float m1 = fminf(t1[it], b4), m2 = fminf(t2[it], b3);
            float m3 = fminf(t3[it], b2), m4 = fminf(t4[it], b1);
            // m is bitonic; clean to ascending
            float u1 = fminf(m1, m3), u3 = fmaxf(m1, m3);
            float u2 = fminf(m2, m4), u4 = fmaxf(m2, m4);
            t1[it] = fminf(u1, u2); t2[it] = fmaxf(u1, u2);
            t3[it] = fminf(u3, u4); t4[it] = fmaxf(u3, u4);
        }
    }
    if (qd == 0) {
        mw[q * 32 + cl]      = t4[0];   // 4th-smallest of wave's 512 for i=cl
        mw[q * 32 + 16 + cl] = t4[1];   // ... for i=16+cl
    }
    __syncthreads();
    // tau = max over 4 waves of (exact 4th of 512-substream) + margin
    if (q == 0 && ln < 32) {
        float m0 = mw[row], m1 = mw[32 + row];
        float m2 = mw[64 + row], m3 = mw[96 + row];
        ldsthr[row] = fmaxf(fmaxf(m0, m1), fmaxf(m2, m3)) + MARGIN;
    }
    __syncthreads();

    // tau for lane's 2 i-rows
    float thrv[ITN];
    #pragma unroll
    for (int it = 0; it < ITN; ++it) thrv[it] = ldsthr[it * 16 + cl];

    // ===== stage B: re-scan, filter d2' < tau into candidate rings ==========
    #pragma unroll 2
    for (int jt = 0; jt < NJT; ++jt) {
        const float* bp = jrow0 + (size_t)jt * (16 * ND);
        float4 va = *(const float4*)(bp);
        float4 vb = *(const float4*)(bp + 4);
        float4 vc = *(const float4*)(bp + 32);
        float4 vd = *(const float4*)(bp + 36);
        f32x4 xq = *(const f32x4*)(ldsx2 + jbase + jt * 16 + qd * 4);
        half8 jlo = cvt8(va, vb);
        half8 jhi = cvt8(vc, vd);
        const int j0 = jbase + jt * 16;

        #pragma unroll
        for (int it = 0; it < ITN; ++it) {
            f32x4 acc;
            acc = __builtin_amdgcn_mfma_f32_16x16x32_f16(
                      jlo, ifr[it][0], (f32x4){0.f, 0.f, 0.f, 0.f}, 0, 0, 0);
            acc = __builtin_amdgcn_mfma_f32_16x16x32_f16(
                      jhi, ifr[it][1], acc, 0, 0, 0);
            #pragma unroll
            for (int r = 0; r < 4; ++r) {
                float d2 = fmaf(-2.f, acc[r], xq[r]);
                if (d2 < thrv[it]) {
                    int rw = it * 16 + cl;
                    int slot = atomicAdd(&rcnt[rw], 1);
                    if (slot < RCAP) ring[rw * RSTR + slot] = j0 + qd * 4 + r;
                }
            }
        }
    }
    __syncthreads();

    // ========== rescue: exact fp32 recompute of candidates ===============
    // row = ln&31; 8 workers per row: (wave q, half jh) take slots w8, w8+8,...
    const int myrow = rowbase + row;
    float4 A[16];
    {
        const float4* ra = (const float4*)(hs + (size_t)myrow * ND);
        #pragma unroll
        for (int k = 0; k < 16; ++k) A[k] = ra[k];
    }
    float x2i;   // ascending chain (exact round-1 i-side value)
    {
        float a0 = 0.f, a1 = 0.f, a2 = 0.f, a3 = 0.f;
        #pragma unroll
        for (int k = 0; k < 16; ++k) {
            a0 = fmaf(A[k].x, A[k].x, a0); a1 = fmaf(A[k].y, A[k].y, a1);
            a2 = fmaf(A[k].z, A[k].z, a2); a3 = fmaf(A[k].w, A[k].w, a3);
        }
        x2i = (a0 + a1) + (a2 + a3);
    }
    float dist[KK]; int idx[KK];
    #pragma unroll
    for (int k = 0; k < KK; ++k) { dist[k] = FLT_MAX; idx[k] = 0; }

    const int cntR = min(rcnt[row], RCAP);
    const int w8 = q * 2 + jh;
    #pragma unroll 1
    for (int k = w8; k < cntR; k += 8) {
        int j = ring[row * RSTR + k];
        const float4* cv = (const float4*)(hs + (size_t)j * ND);
        float a0 = 0.f, a1 = 0.f, a2 = 0.f, a3 = 0.f;
        #pragma unroll
        for (int kk = 0; kk < 16; ++kk) {
            float4 c = cv[kk];
            a0 = fmaf(A[kk].x, c.x, a0); a1 = fmaf(A[kk].y, c.y, a1);
            a2 = fmaf(A[kk].z, c.z, a2); a3 = fmaf(A[kk].w, c.w, a3);
        }
        float dotv = (a0 + a1) + (a2 + a3);
        float d2 = fmaf(-2.0f, dotv, x2i + ldsx2[j]);
        if (lexlt(d2, j, dist[KK - 1], idx[KK - 1]))
            insert16x(dist, idx, d2, j);
    }

    // ---- final exact merge (lex): shuffle level + 2 LDS levels (gated) ----
    #pragma unroll 1
    for (int k = 0; k < KK; ++k) {
        float v  = __shfl(dist[k], row + 32);
        int   jv = __shfl(idx[k],  row + 32);
        bool need = (ln < 32) && lexlt(v, jv, dist[KK - 1], idx[KK - 1]);
        if (!__any(need)) break;
        if (need) insert16x(dist, idx, v, jv);
    }
    __syncthreads();
    #pragma unroll 1
    for (int lvl = 0; lvl < 2; ++lvl) {
        const int step = 1 << lvl;
        const int m    = (step << 1) - 1;
        const bool pub = ((q & m) == step) && ln < 32;
        const int reg  = q >> (lvl + 1);
        if (pub) {
            #pragma unroll
            for (int k = 0; k < KK; ++k) {
                md[(reg * RB + row) * MS + k] = dist[k];
                mi[(reg * RB + row) * MS + k] = idx[k];
            }
        }
        __syncthreads();
        if ((q & m) == 0) {
            #pragma unroll 1
            for (int k = 0; k < KK; ++k) {
                float v  = md[(reg * RB + row) * MS + k];
                int   jv = mi[(reg * RB + row) * MS + k];
                bool need = (ln < 32) && lexlt(v, jv, dist[KK - 1], idx[KK - 1]);
                if (!__any(need)) break;
                if (need) insert16x(dist, idx, v, jv);
            }
        }
        __syncthreads();
    }

    // ---- output (wave 0, lower half) ----
    if (q == 0 && ln < 32) {
        const int off = s * NP;
        const size_t rg = (size_t)off + myrow;
        float* o0 = out + rg * KK;
        float* o1 = out + (size_t)NS * NP * KK + rg * KK;
        float* o2 = out + (size_t)2 * NS * NP * KK + rg * KK;
        #pragma unroll
        for (int k = 0; k < KK; ++k) o0[k] = dist[k];
        #pragma unroll
        for (int k = 0; k < KK; ++k) o1[k] = (float)(idx[k] + off);
        #pragma unroll
        for (int k = 0; k < KK; ++k) o2[k] = (float)(off + myrow);
    }
}

extern "C" void kernel_launch(void* const* d_in, const int* in_sizes, int n_in,
                              void* d_out, int out_size, void* d_ws, size_t ws_size,
                              hipStream_t stream)
{
    const float* h = (const float*)d_in[0];
    float* out = (float*)d_out;
    hipLaunchKernelGGL(knn_fused, dim3(NS * (NP / RB)), dim3(NT), 0, stream,
                       h, out);
}

// Round 8
// 210.735 us; speedup vs baseline: 1.5836x; 1.5836x over previous
//
#include <hip/hip_runtime.h>
#include <hip/hip_fp16.h>
#include <cfloat>

// NearestNeighborGraph: S=16, N=2048, D=64, K=16.
// Round-16: fast-prep + verified r13 knn body.
//  r15 post-mortem: cooperative launch silently no-ops under graph capture
//  (indices all-zero) -> cooperative fusion is unusable here. Revert to the
//  r13 two-kernel structure (passed, 215.8us total / 160.4us knn).
//  r13's prep ran 128 blocks (half the GPU idle, 1 blk/CU): 12MB of traffic
//  at ~250GB/s ~= 45-50us — the bulk of the 55us total-minus-knn delta.
//  New prep: 2048 blocks x 256 threads, 16 rows/block:
//   - f16 conversion: 1 coalesced float4 load + 1 half4 store per thread
//     (elementwise RTN casts -> hh bit-identical to old prep);
//   - x2: threads 0-15 run the byte-identical rotated fmaf chains (L1-hot).
//  knn_mfma is VERBATIM r13 (swapped-MFMA stage A top-4 -> tau, stage B
//  ring filter, exact fp32 rescue, gated merges) -> output identical.

typedef _Float16 half8 __attribute__((ext_vector_type(8)));
typedef _Float16 half4 __attribute__((ext_vector_type(4)));
typedef float    f32x4 __attribute__((ext_vector_type(4)));

constexpr int NS = 16, NP = 2048, ND = 64, KK = 16;
constexpr int NWV = 4;              // waves per block
constexpr int NT  = NWV * 64;       // 256 threads
constexpr int RB  = 32;             // rows (i) per block
constexpr int ITN = RB / 16;        // 2 i-tiles
constexpr int JW  = NP / NWV;       // 512 j per wave
constexpr int NJT = JW / 16;        // 32 j-tiles per wave
constexpr int PF  = 4;              // pipeline depth (static reg slots)
constexpr int MS  = 17;             // merge-tree stride
constexpr int RCAP = 128;           // candidate ring slots per row
constexpr int RSTR = RCAP + 1;      // ring stride
constexpr float MARGIN = 1.0f;

// ---- prep: 16 rows/block; coalesced f16 copy + rotated-chain x2 ----
__global__ __launch_bounds__(256)
void prep_kernel(const float* __restrict__ h, float* __restrict__ x2,
                 _Float16* __restrict__ hh)
{
    const int b = blockIdx.x;                 // 0..2047, 16 rows each
    const int t = threadIdx.x;
    const size_t base = (size_t)b * 16 * ND;  // flat float offset

    // f16 conversion: thread t -> elements [base + 4t, base + 4t + 4)
    float4 v = *(const float4*)(h + base + (size_t)t * 4);
    half4 p;
    p[0] = (_Float16)v.x; p[1] = (_Float16)v.y;
    p[2] = (_Float16)v.z; p[3] = (_Float16)v.w;
    *(half4*)(hh + base + (size_t)t * 4) = p;

    // x2: rotated chain, bit-identical to rounds 1-13 (1 thread per row)
    if (t < 16) {
        const int g = b * 16 + t;             // flat row
        const float4* row = (const float4*)(h + (size_t)g * ND);
        const int ph = g & 15;
        float a0 = 0.f, a1 = 0.f, a2 = 0.f, a3 = 0.f;
        #pragma unroll
        for (int k = 0; k < 16; ++k) {
            float4 u = row[(k + ph) & 15];
            a0 = fmaf(u.x, u.x, a0); a1 = fmaf(u.y, u.y, a1);
            a2 = fmaf(u.z, u.z, a2); a3 = fmaf(u.w, u.w, a3);
        }
        x2[g] = (a0 + a1) + (a2 + a3);
    }
}

// lexicographic (d2, j) insert == top_k tie-break (lowest index on equal d2)
__device__ __forceinline__ bool lexlt(float a, int ja, float b, int jb)
{
    return (a < b) || (a == b && ja < jb);
}
__device__ __forceinline__ void insert16x(float (&d)[KK], int (&ix)[KK],
                                          float v, int j)
{
    #pragma unroll
    for (int p = KK - 1; p > 0; --p) {
        bool sh = lexlt(v, j, d[p - 1], ix[p - 1]);
        bool he = lexlt(v, j, d[p], ix[p]);
        float nd = sh ? d[p - 1] : (he ? v : d[p]);
        int   ni = sh ? ix[p - 1] : (he ? j : ix[p]);
        d[p] = nd; ix[p] = ni;
    }
    if (lexlt(v, j, d[0], ix[0])) { d[0] = v; ix[0] = j; }
}

__global__ __launch_bounds__(NT, 4)
void knn_mfma(const float* __restrict__ h, const _Float16* __restrict__ hh,
              const float* __restrict__ x2g, float* __restrict__ out)
{
    // 8544 floats = 34176 B -> 4 blocks/CU
    __shared__ __align__(16) float smem[8544];
    float* ldsx2  = smem;                    // [0,2048)
    float* mw     = smem + 2048;             // [2048,2176)  4 waves x 32 rows
    float* ldsthr = smem + 2176;             // [2176,2208)
    int*   rcnt   = (int*)(smem + 2208);     // [2208,2240)
    int*   ring   = (int*)(smem + 2240);     // [2240,6368)  32 x 129
    float* md     = smem + 6368;             // [6368,7456)  2 x 32 x 17
    int*   mi     = (int*)(smem + 7456);     // [7456,8544)

    const int t   = threadIdx.x;
    const int ln  = t & 63;
    const int qd  = ln >> 4;                 // j-subslice within wave
    const int cl  = ln & 15;                 // i within 16-tile (swapped D col)
    const int q   = t >> 6;                  // wave id (j-quarter)
    const int row = ln & 31;                 // lane's rescue row
    const int jh  = ln >> 5;                 // rescue worker split
    // XCD sample-affinity swizzle (bijective): sample s -> XCD (s&7),
    // assuming hardware round-robin bid->XCD bid%8 (perf heuristic only).
    const int bid = blockIdx.x;
    const int xcd = bid & 7;
    const int kb  = bid >> 3;                // 0..127
    const int s   = xcd + ((kb & 1) << 3);   // 0..15
    const int rb  = kb >> 1;                 // 0..63
    const int rowbase = rb * RB;             // block's 32 i-rows (sample-local)
    const float*    __restrict__ hs  = h  + (size_t)s * NP * ND;
    const _Float16* __restrict__ hhs = hh + (size_t)s * NP * ND;

    // stage sample x2; init ring counts
    ((float4*)ldsx2)[t]       = ((const float4*)(x2g + s * NP))[t];
    ((float4*)ldsx2)[t + 256] = ((const float4*)(x2g + s * NP))[t + 256];
    if (t < RB) rcnt[t] = 0;

    // i-fragments (the MFMA *B* operand): lane holds I[n=cl][k=qd*8..+7]
    half8 ifr[ITN][2];
    #pragma unroll
    for (int it = 0; it < ITN; ++it) {
        const _Float16* ap = hhs + (size_t)(rowbase + it * 16 + cl) * ND + qd * 8;
        ifr[it][0] = *(const half8*)(ap);
        ifr[it][1] = *(const half8*)(ap + 32);
    }
    __syncthreads();

    const int jbase = q * JW;
    const _Float16* __restrict__ jrow0 = hhs + (size_t)(jbase + cl) * ND + qd * 8;

    auto loadj = [&](int jt, half8 &lo, half8 &hi, f32x4 &xq) {
        const _Float16* bp = jrow0 + (size_t)jt * (16 * ND);
        lo = *(const half8*)(bp);
        hi = *(const half8*)(bp + 32);
        xq = *(const f32x4*)(ldsx2 + jbase + jt * 16 + qd * 4);
    };

    // ===== stage A: swapped MFMA scan; per-lane top-4 of d2' in registers ====
    // d2' = x2j - 2*dot  (x2i dropped: per-row constant, rank-invariant).
    float t1[ITN], t2[ITN], t3[ITN], t4[ITN];
    #pragma unroll
    for (int it = 0; it < ITN; ++it)
        { t1[it] = FLT_MAX; t2[it] = FLT_MAX; t3[it] = FLT_MAX; t4[it] = FLT_MAX; }

    {
        half8 plo[PF], phi[PF]; f32x4 pxq[PF];
        #pragma unroll
        for (int p = 0; p < PF; ++p) loadj(p, plo[p], phi[p], pxq[p]);

        for (int t0 = 0; t0 < NJT; t0 += PF) {
            #pragma unroll
            for (int p = 0; p < PF; ++p) {
                half8 clo = plo[p], chi = phi[p]; f32x4 cxq = pxq[p];
                int nx = t0 + p + PF;
                if (nx < NJT) loadj(nx, plo[p], phi[p], pxq[p]);
                #pragma unroll
                for (int it = 0; it < ITN; ++it) {
                    f32x4 acc;
                    acc = __builtin_amdgcn_mfma_f32_16x16x32_f16(
                              clo, ifr[it][0], (f32x4){0.f, 0.f, 0.f, 0.f}, 0, 0, 0);
                    acc = __builtin_amdgcn_mfma_f32_16x16x32_f16(
                              chi, ifr[it][1], acc, 0, 0, 0);
                    #pragma unroll
                    for (int r = 0; r < 4; ++r) {
                        float v  = fmaf(-2.f, acc[r], cxq[r]);
                        float n1 = fminf(t1[it], v);
                        float n2 = __builtin_amdgcn_fmed3f(t1[it], t2[it], v);
                        float n3 = __builtin_amdgcn_fmed3f(t2[it], t3[it], v);
                        float n4 = __builtin_amdgcn_fmed3f(t3[it], t4[it], v);
                        t1[it] = n1; t2[it] = n2; t3[it] = n3; t4[it] = n4;
                    }
                }
            }
        }
    }

    // merge the 4 qd sub-lists (sorted 4s) -> wave's exact top-4 of 512
    #pragma unroll
    for (int it = 0; it < ITN; ++it) {
        #pragma unroll
        for (int lvl = 0; lvl < 2; ++lvl) {
            const int mask = 16 << lvl;
            float b1 = __shfl_xor(t1[it], mask), b2 = __shfl_xor(t2[it], mask);
            float b3 = __shfl_xor(t3[it], mask), b4 = __shfl_xor(t4[it], mask);
            float m1 = fminf(t1[it], b4), m2 = fminf(t2[it], b3);
            float m3 = fminf(t3[it], b2), m4 = fminf(t4[it], b1);
            // m is bitonic; clean to ascending
            float u1 = fminf(m1, m3), u3 = fmaxf(m1, m3);
            float u2 = fminf(m2, m4), u4 = fmaxf(m2, m4);
            t1[it] = fminf(u1, u2); t2[it] = fmaxf(u1, u2);
            t3[it] = fminf(u3, u4); t4[it] = fmaxf(u3, u4);
        }
    }
    if (qd == 0) {
        mw[q * 32 + cl]      = t4[0];   // 4th-smallest of wave's 512 for i=cl
        mw[q * 32 + 16 + cl] = t4[1];   // ... for i=16+cl
    }
    __syncthreads();
    // tau = max over 4 waves of (exact 4th of 512-substream) + margin
    if (q == 0 && ln < 32) {
        float m0 = mw[row], m1 = mw[32 + row];
        float m2 = mw[64 + row], m3 = mw[96 + row];
        ldsthr[row] = fmaxf(fmaxf(m0, m1), fmaxf(m2, m3)) + MARGIN;
    }
    __syncthreads();

    // tau for lane's 2 i-rows
    float thrv[ITN];
    #pragma unroll
    for (int it = 0; it < ITN; ++it) thrv[it] = ldsthr[it * 16 + cl];

    // ===== stage B: re-scan, filter d2' < tau into candidate rings ==========
    {
        half8 plo[PF], phi[PF]; f32x4 pxq[PF];
        #pragma unroll
        for (int p = 0; p < PF; ++p) loadj(p, plo[p], phi[p], pxq[p]);

        for (int t0 = 0; t0 < NJT; t0 += PF) {
            #pragma unroll
            for (int p = 0; p < PF; ++p) {
                half8 clo = plo[p], chi = phi[p]; f32x4 cxq = pxq[p];
                const int j0 = jbase + (t0 + p) * 16;
                int nx = t0 + p + PF;
                if (nx < NJT) loadj(nx, plo[p], phi[p], pxq[p]);
                #pragma unroll
                for (int it = 0; it < ITN; ++it) {
                    f32x4 acc;
                    acc = __builtin_amdgcn_mfma_f32_16x16x32_f16(
                              clo, ifr[it][0], (f32x4){0.f, 0.f, 0.f, 0.f}, 0, 0, 0);
                    acc = __builtin_amdgcn_mfma_f32_16x16x32_f16(
                              chi, ifr[it][1], acc, 0, 0, 0);
                    #pragma unroll
                    for (int r = 0; r < 4; ++r) {
                        float d2 = fmaf(-2.f, acc[r], cxq[r]);
                        if (d2 < thrv[it]) {
                            int rw = it * 16 + cl;
                            int slot = atomicAdd(&rcnt[rw], 1);
                            if (slot < RCAP) ring[rw * RSTR + slot] = j0 + qd * 4 + r;
                        }
                    }
                }
            }
        }
    }
    __syncthreads();

    // ========== rescue: exact fp32 recompute of candidates ===============
    // row = ln&31; 8 workers per row: (wave q, half jh) take slots w8, w8+8,...
    const int myrow = rowbase + row;
    float4 A[16];
    {
        const float4* ra = (const float4*)(hs + (size_t)myrow * ND);
        #pragma unroll
        for (int k = 0; k < 16; ++k) A[k] = ra[k];
    }
    float x2i;   // ascending chain (exact round-1 i-side value)
    {
        float a0 = 0.f, a1 = 0.f, a2 = 0.f, a3 = 0.f;
        #pragma unroll
        for (int k = 0; k < 16; ++k) {
            a0 = fmaf(A[k].x, A[k].x, a0); a1 = fmaf(A[k].y, A[k].y, a1);
            a2 = fmaf(A[k].z, A[k].z, a2); a3 = fmaf(A[k].w, A[k].w, a3);
        }
        x2i = (a0 + a1) + (a2 + a3);
    }
    float dist[KK]; int idx[KK];
    #pragma unroll
    for (int k = 0; k < KK; ++k) { dist[k] = FLT_MAX; idx[k] = 0; }

    const int cntR = min(rcnt[row], RCAP);
    const int w8 = q * 2 + jh;
    #pragma unroll 1
    for (int k = w8; k < cntR; k += 8) {
        int j = ring[row * RSTR + k];
        const float4* cv = (const float4*)(hs + (size_t)j * ND);
        float a0 = 0.f, a1 = 0.f, a2 = 0.f, a3 = 0.f;
        #pragma unroll
        for (int kk = 0; kk < 16; ++kk) {
            float4 c = cv[kk];
            a0 = fmaf(A[kk].x, c.x, a0); a1 = fmaf(A[kk].y, c.y, a1);
            a2 = fmaf(A[kk].z, c.z, a2); a3 = fmaf(A[kk].w, c.w, a3);
        }
        float dotv = (a0 + a1) + (a2 + a3);
        float d2 = fmaf(-2.0f, dotv, x2i + ldsx2[j]);
        if (lexlt(d2, j, dist[KK - 1], idx[KK - 1]))
            insert16x(dist, idx, d2, j);
    }

    // ---- final exact merge (lex): shuffle level + 2 LDS levels (gated) ----
    #pragma unroll 1
    for (int k = 0; k < KK; ++k) {
        float v  = __shfl(dist[k], row + 32);
        int   jv = __shfl(idx[k],  row + 32);
        bool need = (ln < 32) && lexlt(v, jv, dist[KK - 1], idx[KK - 1]);
        if (!__any(need)) break;
        if (need) insert16x(dist, idx, v, jv);
    }
    __syncthreads();
    #pragma unroll 1
    for (int lvl = 0; lvl < 2; ++lvl) {
        const int step = 1 << lvl;
        const int m    = (step << 1) - 1;
        const bool pub = ((q & m) == step) && ln < 32;
        const int reg  = q >> (lvl + 1);
        if (pub) {
            #pragma unroll
            for (int k = 0; k < KK; ++k) {
                md[(reg * RB + row) * MS + k] = dist[k];
                mi[(reg * RB + row) * MS + k] = idx[k];
            }
        }
        __syncthreads();
        if ((q & m) == 0) {
            #pragma unroll 1
            for (int k = 0; k < KK; ++k) {
                float v  = md[(reg * RB + row) * MS + k];
                int   jv = mi[(reg * RB + row) * MS + k];
                bool need = (ln < 32) && lexlt(v, jv, dist[KK - 1], idx[KK - 1]);
                if (!__any(need)) break;
                if (need) insert16x(dist, idx, v, jv);
            }
        }
        __syncthreads();
    }

    // ---- output (wave 0, lower half) ----
    if (q == 0 && ln < 32) {
        const int off = s * NP;
        const size_t rg = (size_t)off + myrow;
        float* o0 = out + rg * KK;
        float* o1 = out + (size_t)NS * NP * KK + rg * KK;
        float* o2 = out + (size_t)2 * NS * NP * KK + rg * KK;
        #pragma unroll
        for (int k = 0; k < KK; ++k) o0[k] = dist[k];
        #pragma unroll
        for (int k = 0; k < KK; ++k) o1[k] = (float)(idx[k] + off);
        #pragma unroll
        for (int k = 0; k < KK; ++k) o2[k] = (float)(off + myrow);
    }
}

extern "C" void kernel_launch(void* const* d_in, const int* in_sizes, int n_in,
                              void* d_out, int out_size, void* d_ws, size_t ws_size,
                              hipStream_t stream)
{
    const float* h = (const float*)d_in[0];
    float* out = (float*)d_out;
    float*    x2 = (float*)d_ws;                     // 32768 floats (128 KB)
    _Float16* hh = (_Float16*)(x2 + NS * NP);        // 16*2048*64 halves (4 MB)

    hipLaunchKernelGGL(prep_kernel, dim3(NS * NP / 16), dim3(256), 0, stream,
                       h, x2, hh);
    hipLaunchKernelGGL(knn_mfma, dim3(NS * (NP / RB)), dim3(NT), 0, stream,
                       h, hh, x2, out);
}